// Round 11
// baseline (825.834 us; speedup 1.0000x reference)
//
#include <hip/hip_runtime.h>

typedef unsigned short u16;
typedef __attribute__((ext_vector_type(8))) short bf16x8;
typedef __attribute__((ext_vector_type(4))) float f32x4;

__device__ inline u16 f2bf(float f) {
  unsigned int u = __float_as_uint(f);
  u += 0x7fffu + ((u >> 16) & 1u);
  return (u16)(u >> 16);
}
__device__ inline float bf2f(u16 v) {
  return __uint_as_float((unsigned)v << 16);
}

__device__ inline uint4 pack8(float4 a, float4 b) {
  uint4 r;
  r.x = (unsigned)f2bf(a.x) | ((unsigned)f2bf(a.y) << 16);
  r.y = (unsigned)f2bf(a.z) | ((unsigned)f2bf(a.w) << 16);
  r.z = (unsigned)f2bf(b.x) | ((unsigned)f2bf(b.y) << 16);
  r.w = (unsigned)f2bf(b.z) | ((unsigned)f2bf(b.w) << 16);
  return r;
}

// ---- fused one-shot weight transpose ----
struct TransDesc {
  const float* src[9];
  u16* dst[9];
  int R[9];
  int C[9];
  int pre[10];
};

__global__ void transpose_all_kernel(TransDesc td) {
  int t = blockIdx.x * 256 + threadIdx.x;
  if (t >= td.pre[9]) return;
  int seg = 0;
  while (t >= td.pre[seg + 1]) ++seg;
  int local = t - td.pre[seg];
  int C = td.C[seg], R = td.R[seg];
  int r = local / C, c = local - r * C;
  td.dst[seg][(size_t)c * R + r] = f2bf(td.src[seg][local]);
}

// ---------------- CSR slot build ----------------
__global__ void count_kernel(const int* __restrict__ fi,
                             const int* __restrict__ ti,
                             int* __restrict__ cnt, int E) {
  int e = blockIdx.x * 256 + threadIdx.x;
  if (e < E) {
    atomicAdd(&cnt[ti[e]], 1);
    atomicAdd(&cnt[fi[e]], 1);
  }
}

__global__ void scan1_kernel(const int* __restrict__ cnt,
                             int* __restrict__ partial, int N, int chunk) {
  __shared__ int sdata[256];
  int b = blockIdx.x, t = threadIdx.x;
  int base = b * chunk;
  int sum = 0;
  for (int i = t; i < chunk; i += 256) {
    int idx = base + i;
    if (idx < N) sum += cnt[idx];
  }
  sdata[t] = sum;
  __syncthreads();
  for (int s2 = 128; s2 > 0; s2 >>= 1) {
    if (t < s2) sdata[t] += sdata[t + s2];
    __syncthreads();
  }
  if (t == 0) partial[b] = sdata[0];
}

__global__ void scan2_kernel(int* __restrict__ partial) {
  __shared__ int s[256];
  int t = threadIdx.x;
  int own = partial[t];
  s[t] = own;
  __syncthreads();
  for (int d2 = 1; d2 < 256; d2 <<= 1) {
    int v = (t >= d2) ? s[t - d2] : 0;
    __syncthreads();
    s[t] += v;
    __syncthreads();
  }
  partial[t] = s[t] - own;  // exclusive
}

__global__ void scan3_kernel(const int* __restrict__ cnt,
                             const int* __restrict__ partialEx,
                             int* __restrict__ cursor, int N, int chunk) {
  __shared__ int s[256];
  int b = blockIdx.x, t = threadIdx.x;
  int base = b * chunk;
  int own = (t < chunk && base + t < N) ? cnt[base + t] : 0;
  s[t] = own;
  __syncthreads();
  for (int d2 = 1; d2 < 256; d2 <<= 1) {
    int v = (t >= d2) ? s[t - d2] : 0;
    __syncthreads();
    s[t] += v;
    __syncthreads();
  }
  int ex = s[t] - own + partialEx[b];
  if (t < chunk && base + t < N) cursor[base + t] = ex;
}

__global__ void slot_kernel(const int* __restrict__ fi,
                            const int* __restrict__ ti,
                            int* __restrict__ cursor, int* __restrict__ s_nbr,
                            int* __restrict__ s_eid, int* __restrict__ s_dest,
                            int E) {
  int e = blockIdx.x * 256 + threadIdx.x;
  if (e < E) {
    int f = fi[e], t2 = ti[e];
    int p0 = atomicAdd(&cursor[t2], 1);
    s_nbr[p0] = f;
    s_eid[p0] = e;
    s_dest[p0] = t2;
    int p1 = atomicAdd(&cursor[f], 1);
    s_nbr[p1] = t2;
    s_eid[p1] = e;
    s_dest[p1] = f;
  }
}

// ---- shared MFMA helpers (verified R1-R10) ----
__device__ inline void stage_w_512(u16* sW, const u16* __restrict__ src,
                                   int roww, int colofs, int tid) {
  int n = tid >> 2, quarter = tid & 3;
  const u16* s = src + (size_t)n * roww + colofs + quarter * 32;
#pragma unroll
  for (int q = 0; q < 4; ++q) {
    uint4 v = *(const uint4*)(s + q * 8);
    int byte = n * 256 + ((quarter * 64 + q * 16) ^ ((n & 7) << 4));
    *(uint4*)((char*)sW + byte) = v;
  }
}

__device__ inline void mfma_pass(const u16* A, const u16* W, f32x4 acc[8],
                                 int w, int lane) {
  const int cA = lane & 15;
  const int ko = (lane >> 4) * 8;
  const int arow = 16 * w + cA;
#pragma unroll
  for (int kk = 0; kk < 4; ++kk) {
    int ka = (kk * 32 + ko) * 2;
    int sx = ka ^ ((cA & 7) << 4);
    bf16x8 a = *(const bf16x8*)((const char*)A + arow * 256 + sx);
#pragma unroll
    for (int nt = 0; nt < 8; ++nt) {
      bf16x8 bb = *(const bf16x8*)((const char*)W + (nt * 16 + cA) * 256 + sx);
      acc[nt] = __builtin_amdgcn_mfma_f32_16x16x32_bf16(a, bb, acc[nt], 0, 0, 0);
    }
  }
}

// MFMA pass with B-fragments read straight from (L2-hot) global weights.
// Safe ONLY when each block reads the weights once (gru3), not per-tile (R7!).
__device__ inline void mfma_pass_g(const u16* A, const u16* __restrict__ Wg,
                                   f32x4 acc[8], int w, int lane) {
  const int cA = lane & 15;
  const int ko = (lane >> 4) * 8;
  const int arow = 16 * w + cA;
#pragma unroll
  for (int kk = 0; kk < 4; ++kk) {
    int ka = (kk * 32 + ko) * 2;
    int sx = ka ^ ((cA & 7) << 4);
    bf16x8 a = *(const bf16x8*)((const char*)A + arow * 256 + sx);
#pragma unroll
    for (int nt = 0; nt < 8; ++nt) {
      bf16x8 bb = *(const bf16x8*)(Wg + (size_t)(nt * 16 + cA) * 128 +
                                   kk * 32 + ko);
      acc[nt] = __builtin_amdgcn_mfma_f32_16x16x32_bf16(a, bb, acc[nt], 0, 0, 0);
    }
  }
}

__device__ inline void write_h_lds(u16* sH, const f32x4 acc[8], int w,
                                   int lane) {
#pragma unroll
  for (int nt = 0; nt < 8; ++nt) {
    int col = nt * 16 + (lane & 15);
#pragma unroll
    for (int i = 0; i < 4; ++i) {
      int rr = 16 * w + ((lane >> 4) * 4) + i;
      *(u16*)((char*)sH + rr * 256 + ((col * 2) ^ ((rr & 7) << 4))) =
          f2bf(acc[nt][i]);
    }
  }
}

// Fused first-layer GEMMs, 128 rows / 512 threads.
// blocks [0,Nb): Pa/Pb = bf16(ns@W1a/b); blocks [Nb,Nb+Eb): EFm = bf16(ef@W1c+b1)
__global__ __launch_bounds__(512) void gemm1_kernel(
    const float* __restrict__ ns, const float* __restrict__ ef,
    const u16* __restrict__ Wt1, const float* __restrict__ b1,
    u16* __restrict__ Pa, u16* __restrict__ Pb, u16* __restrict__ EFm, int N,
    int E, int Nb) {
  __shared__ u16 sA[128 * 128];
  __shared__ u16 sW[128 * 128];
  const int tid = threadIdx.x;
  const int lane = tid & 63;
  const int w = tid >> 6;
  if ((int)blockIdx.x < Nb) {
    const int r0 = blockIdx.x * 128;
    {
      int row = tid >> 2, seg = tid & 3;
      int rr = r0 + row;
      if (rr >= N) rr = N - 1;
      const float4* sx = (const float4*)(ns + (size_t)rr * 128 + seg * 32);
#pragma unroll
      for (int q = 0; q < 4; ++q) {
        int byte = row * 256 + ((seg * 64 + q * 16) ^ ((row & 7) << 4));
        *(uint4*)((char*)sA + byte) = pack8(sx[q * 2], sx[q * 2 + 1]);
      }
    }
    stage_w_512(sW, Wt1, 384, 0, tid);
    __syncthreads();
    f32x4 accA[8] = {};
    mfma_pass(sA, sW, accA, w, lane);
    __syncthreads();
    stage_w_512(sW, Wt1, 384, 128, tid);
    __syncthreads();
    f32x4 accB[8] = {};
    mfma_pass(sA, sW, accB, w, lane);
#pragma unroll
    for (int nt = 0; nt < 8; ++nt) {
      int col = nt * 16 + (lane & 15);
#pragma unroll
      for (int i = 0; i < 4; ++i) {
        int rr = 16 * w + ((lane >> 4) * 4) + i;
        int row = r0 + rr;
        if (row < N) {
          Pa[(size_t)row * 128 + col] = f2bf(accA[nt][i]);
          Pb[(size_t)row * 128 + col] = f2bf(accB[nt][i]);
        }
      }
    }
  } else {
    const int r0 = (blockIdx.x - Nb) * 128;
    {
      int row = tid >> 2, seg = tid & 3;
      int rr = r0 + row;
      if (rr >= E) rr = E - 1;
      const float4* sx = (const float4*)(ef + (size_t)rr * 128 + seg * 32);
#pragma unroll
      for (int q = 0; q < 4; ++q) {
        int byte = row * 256 + ((seg * 64 + q * 16) ^ ((row & 7) << 4));
        *(uint4*)((char*)sA + byte) = pack8(sx[q * 2], sx[q * 2 + 1]);
      }
    }
    stage_w_512(sW, Wt1, 384, 256, tid);
    __syncthreads();
    f32x4 acc[8] = {};
    mfma_pass(sA, sW, acc, w, lane);
    __syncthreads();  // all reads of sA done before overwrite
#pragma unroll
    for (int nt = 0; nt < 8; ++nt) {
      int col = nt * 16 + (lane & 15);
      float bv = b1[col];
#pragma unroll
      for (int i = 0; i < 4; ++i) {
        int rr = 16 * w + ((lane >> 4) * 4) + i;
        *(u16*)((char*)sA + rr * 256 + ((col * 2) ^ ((rr & 7) << 4))) =
            f2bf(acc[nt][i] + bv);
      }
    }
    __syncthreads();
#pragma unroll
    for (int it = 0; it < 4; ++it) {
      int task = tid + (it << 9);
      int row = task >> 4, c8 = task & 15;
      int gr = r0 + row;
      if (gr < E) {
        uint4 v = *(const uint4*)((const char*)sA + row * 256 +
                                  ((c8 << 4) ^ ((row & 7) << 4)));
        *(uint4*)(EFm + (size_t)gr * 128 + (c8 << 3)) = v;
      }
    }
  }
}

// Destination-sorted edge MLP, 64 slots/tile, W2/W3 in LDS -> 2 blocks/CU.
// (unchanged from R10 — verified, near its structural floor)
__global__ __launch_bounds__(512, 2) void edge_csr2_kernel(
    const u16* __restrict__ EFm, const int* __restrict__ s_nbr,
    const int* __restrict__ s_eid, const int* __restrict__ s_dest,
    const u16* __restrict__ Wt2, const u16* __restrict__ Wt3,
    const u16* __restrict__ Pa, const u16* __restrict__ Pb,
    const float* __restrict__ b2, const float* __restrict__ b3,
    float* __restrict__ aggf, int nslots, int ntiles) {
  __shared__ u16 sW2[128 * 128];
  __shared__ u16 sW3[128 * 128];
  __shared__ u16 sH[64 * 128];
  const int tid = threadIdx.x;
  const int lane = tid & 63;
  const int wv = tid >> 6;
  const int mw = wv >> 1;
  const int nw = wv & 1;
  const int l15 = lane & 15;
  const int lhi = lane >> 4;

  stage_w_512(sW2, Wt2, 128, 0, tid);
  stage_w_512(sW3, Wt3, 128, 0, tid);
  float b2f[4], b3f[4];
#pragma unroll
  for (int nt = 0; nt < 4; ++nt) {
    int col = (nw << 6) + (nt << 4) + l15;
    b2f[nt] = b2[col];
    b3f[nt] = b3[col];
  }
  __syncthreads();

  const int ra = (mw << 4) + l15;

  for (int t = blockIdx.x; t < ntiles; t += gridDim.x) {
    const int r0 = t << 6;
#pragma unroll
    for (int it = 0; it < 2; ++it) {
      int task = tid + (it << 9);
      int row = task >> 4;
      int c8 = task & 15;
      int r = r0 + row;
      int rc = r < nslots ? r : nslots - 1;
      int nbr = s_nbr[rc], eid = s_eid[rc], dst = s_dest[rc];
      uint4 efv = *(const uint4*)(EFm + (size_t)eid * 128 + (c8 << 3));
      uint4 pav = *(const uint4*)(Pa + (size_t)nbr * 128 + (c8 << 3));
      uint4 pbv = *(const uint4*)(Pb + (size_t)dst * 128 + (c8 << 3));
      const u16* pe = (const u16*)&efv;
      const u16* pa = (const u16*)&pav;
      const u16* pb = (const u16*)&pbv;
      unsigned o[4];
#pragma unroll
      for (int j = 0; j < 4; ++j) {
        float v0 = fmaxf(bf2f(pe[2 * j]) + bf2f(pa[2 * j]) + bf2f(pb[2 * j]), 0.f);
        float v1 = fmaxf(bf2f(pe[2 * j + 1]) + bf2f(pa[2 * j + 1]) + bf2f(pb[2 * j + 1]), 0.f);
        o[j] = (unsigned)f2bf(v0) | ((unsigned)f2bf(v1) << 16);
      }
      *(uint4*)((char*)sH + row * 256 + ((c8 << 4) ^ ((row & 7) << 4))) = *(uint4*)o;
    }
    __syncthreads();
    bf16x8 hA[4];
#pragma unroll
    for (int kk = 0; kk < 4; ++kk) {
      int sx = ((kk << 6) + (lhi << 4)) ^ ((ra & 7) << 4);
      hA[kk] = *(const bf16x8*)((const char*)sH + ra * 256 + sx);
    }
    f32x4 acc[4] = {};
#pragma unroll
    for (int kk = 0; kk < 4; ++kk) {
#pragma unroll
      for (int nt = 0; nt < 4; ++nt) {
        int c = (nw << 6) + (nt << 4) + l15;
        int sx = ((kk << 6) + (lhi << 4)) ^ ((c & 7) << 4);
        bf16x8 bb = *(const bf16x8*)((const char*)sW2 + c * 256 + sx);
        acc[nt] = __builtin_amdgcn_mfma_f32_16x16x32_bf16(hA[kk], bb, acc[nt], 0, 0, 0);
      }
    }
    __syncthreads();
#pragma unroll
    for (int i = 0; i < 4; ++i) {
      int rl = (mw << 4) + (lhi << 2) + i;
#pragma unroll
      for (int nt = 0; nt < 4; ++nt) {
        int col = (nw << 6) + (nt << 4) + l15;
        float v = fmaxf(acc[nt][i] + b2f[nt], 0.f);
        *(u16*)((char*)sH + rl * 256 + ((col * 2) ^ ((rl & 7) << 4))) = f2bf(v);
        acc[nt][i] = 0.f;
      }
    }
    __syncthreads();
#pragma unroll
    for (int kk = 0; kk < 4; ++kk) {
      int sx = ((kk << 6) + (lhi << 4)) ^ ((ra & 7) << 4);
      hA[kk] = *(const bf16x8*)((const char*)sH + ra * 256 + sx);
    }
#pragma unroll
    for (int kk = 0; kk < 4; ++kk) {
#pragma unroll
      for (int nt = 0; nt < 4; ++nt) {
        int c = (nw << 6) + (nt << 4) + l15;
        int sx = ((kk << 6) + (lhi << 4)) ^ ((c & 7) << 4);
        bf16x8 bb = *(const bf16x8*)((const char*)sW3 + c * 256 + sx);
        acc[nt] = __builtin_amdgcn_mfma_f32_16x16x32_bf16(hA[kk], bb, acc[nt], 0, 0, 0);
      }
    }
    __syncthreads();
#pragma unroll
    for (int i = 0; i < 4; ++i) {
      int rl = (mw << 4) + (lhi << 2) + i;
#pragma unroll
      for (int nt = 0; nt < 4; ++nt) {
        int col = (nw << 6) + (nt << 4) + l15;
        *(u16*)((char*)sH + rl * 256 + ((col * 2) ^ ((rl & 7) << 4))) =
            f2bf(acc[nt][i] + b3f[nt]);
      }
    }
    __syncthreads();
    {
      int c = tid & 127, q = tid >> 7;
      float s = 0.f;
      int prev = -1;
      int rbeg = q << 4;
#pragma unroll 4
      for (int rr = rbeg; rr < rbeg + 16; ++rr) {
        int r = r0 + rr;
        int d = (r < nslots) ? s_dest[r] : -1;
        if (d != prev) {
          if (prev >= 0) unsafeAtomicAdd(&aggf[(size_t)prev * 128 + c], s);
          prev = d;
          s = 0.f;
        }
        if (d >= 0)
          s += bf2f(*(const u16*)((const char*)sH + rr * 256 +
                                  ((c * 2) ^ ((rr & 7) << 4))));
      }
      if (prev >= 0) unsafeAtomicAdd(&aggf[(size_t)prev * 128 + c], s);
    }
    __syncthreads();
  }
}

// Barrier-free fused 3-GRU chain: 256 threads, 64 rows, wave-private rows.
// Weights read per-MFMA from L2-hot global (each block reads them ONCE).
__global__ __launch_bounds__(256, 2) void gru3_kernel(
    const float* __restrict__ ns, const float* __restrict__ aggf,
    const u16* __restrict__ g0W, const u16* __restrict__ g0U,
    const u16* __restrict__ g1W, const u16* __restrict__ g1U,
    const u16* __restrict__ g2W, const u16* __restrict__ g2U,
    const float* __restrict__ b0, const float* __restrict__ c0,
    const float* __restrict__ b1, const float* __restrict__ c1,
    const float* __restrict__ b2, const float* __restrict__ c2,
    float* __restrict__ out, int N) {
  __shared__ u16 sX[64 * 128];  // ns -> h1 (wave-private rows)
  __shared__ u16 sG[64 * 128];  // agg -> h2
  const int tid = threadIdx.x;
  const int lane = tid & 63;
  const int w = tid >> 6;
  const int r0 = blockIdx.x * 64;
  const int l15 = lane & 15;

  // wave-private stage: wave w stages rows 16w..16w+15
  {
    int row = 16 * w + (lane >> 2);
    int seg = lane & 3;
    int rr = r0 + row;
    if (rr >= N) rr = N - 1;
    const float4* sx = (const float4*)(ns + (size_t)rr * 128 + seg * 32);
    const float4* sh = (const float4*)(aggf + (size_t)rr * 128 + seg * 32);
#pragma unroll
    for (int q = 0; q < 4; ++q) {
      int byte = row * 256 + ((seg * 64 + q * 16) ^ ((row & 7) << 4));
      *(uint4*)((char*)sX + byte) = pack8(sx[q * 2], sx[q * 2 + 1]);
      *(uint4*)((char*)sG + byte) = pack8(sh[q * 2], sh[q * 2 + 1]);
    }
  }

  float hpf[8][4];  // f32 passthrough of previous h

#define GRU_BODY(XL, HL, GW, GU, BB, CC, HP_EXPR, EMIT)                       \
  {                                                                           \
    f32x4 gr[8] = {}, gn[8] = {}, hn[8] = {};                                 \
    mfma_pass_g((XL), (GW) + 0 * 16384, gr, w, lane);                         \
    mfma_pass_g((HL), (GU) + 0 * 16384, gr, w, lane);                         \
    mfma_pass_g((XL), (GW) + 2 * 16384, gn, w, lane);                         \
    mfma_pass_g((HL), (GU) + 2 * 16384, hn, w, lane);                         \
    _Pragma("unroll") for (int nt = 0; nt < 8; ++nt) {                        \
      int col = nt * 16 + l15;                                                \
      float brc = (BB)[col] + (CC)[col];                                      \
      float bi = (BB)[256 + col];                                             \
      float bc2 = (CC)[256 + col];                                            \
      _Pragma("unroll") for (int i = 0; i < 4; ++i) {                         \
        float rg = 1.f / (1.f + __expf(-(gr[nt][i] + brc)));                  \
        float pre = gn[nt][i] + bi + rg * (hn[nt][i] + bc2);                  \
        gn[nt][i] = 2.f / (1.f + __expf(-2.f * pre)) - 1.f;                   \
      }                                                                       \
    }                                                                         \
    _Pragma("unroll") for (int nt = 0; nt < 8; ++nt)                          \
        _Pragma("unroll") for (int i = 0; i < 4; ++i) gr[nt][i] = 0.f;        \
    mfma_pass_g((XL), (GW) + 1 * 16384, gr, w, lane);                         \
    mfma_pass_g((HL), (GU) + 1 * 16384, gr, w, lane);                         \
    _Pragma("unroll") for (int nt = 0; nt < 8; ++nt) {                        \
      int col = nt * 16 + l15;                                                \
      float bzc = (BB)[128 + col] + (CC)[128 + col];                          \
      _Pragma("unroll") for (int i = 0; i < 4; ++i) {                         \
        float zg = 1.f / (1.f + __expf(-(gr[nt][i] + bzc)));                  \
        float hv = (1.f - zg) * gn[nt][i] + zg * (HP_EXPR);                   \
        EMIT;                                                                 \
      }                                                                       \
    }                                                                         \
  }

  // GRU0: x=ns(sX), h=agg(sG); passthrough = aggf (f32 global)
  {
    f32x4 h1[8];
    GRU_BODY(sX, sG, g0W, g0U, b0, c0,
             aggf[(size_t)(r0 + 16 * w + ((lane >> 4) << 2) + i < N
                               ? r0 + 16 * w + ((lane >> 4) << 2) + i
                               : N - 1) * 128 + col],
             { h1[nt][i] = hv; hpf[nt][i] = hv; })
    write_h_lds(sX, h1, w, lane);  // sX := h1 (own rows; in-wave ordering)
  }
  // GRU1: x=agg(sG), h=h1(sX); passthrough = h1 (hpf)
  {
    f32x4 h2[8];
    GRU_BODY(sG, sX, g1W, g1U, b1, c1, hpf[nt][i],
             { h2[nt][i] = hv; })
    write_h_lds(sG, h2, w, lane);  // sG := h2
#pragma unroll
    for (int nt = 0; nt < 8; ++nt)
#pragma unroll
      for (int i = 0; i < 4; ++i) hpf[nt][i] = h2[nt][i];
  }
  // GRU2: x=h1(sX), h=h2(sG); passthrough = h2 (hpf) -> out
  GRU_BODY(sX, sG, g2W, g2U, b2, c2, hpf[nt][i], {
    int row = r0 + 16 * w + ((lane >> 4) << 2) + i;
    if (row < N) out[(size_t)row * 128 + col] = hv;
  })
#undef GRU_BODY
}

extern "C" void kernel_launch(void* const* d_in, const int* in_sizes, int n_in,
                              void* d_out, int out_size, void* d_ws,
                              size_t ws_size, hipStream_t stream) {
  const float* ns = (const float*)d_in[0];
  const float* ef = (const float*)d_in[1];
  const int* from_idx = (const int*)d_in[2];
  const int* to_idx = (const int*)d_in[3];
  const float* mW1 = (const float*)d_in[5];
  const float* mb1 = (const float*)d_in[6];
  const float* mW2 = (const float*)d_in[7];
  const float* mb2 = (const float*)d_in[8];
  const float* mW3 = (const float*)d_in[9];
  const float* mb3 = (const float*)d_in[10];
  const float* gW[3] = {(const float*)d_in[11], (const float*)d_in[15], (const float*)d_in[19]};
  const float* gU[3] = {(const float*)d_in[12], (const float*)d_in[16], (const float*)d_in[20]};
  const float* gb[3] = {(const float*)d_in[13], (const float*)d_in[17], (const float*)d_in[21]};
  const float* gc[3] = {(const float*)d_in[14], (const float*)d_in[18], (const float*)d_in[22]};

  const int N = in_sizes[0] / 128;
  const int E = in_sizes[1] / 128;
  const int nslots = 2 * E;

  char* base = (char*)d_ws;
  size_t cur = 0;
  auto alloc = [&](size_t bytes) {
    size_t p = cur;
    cur = (cur + bytes + 255) & ~(size_t)255;
    return (void*)(base + p);
  };
  float* aggf = (float*)alloc((size_t)N * 128 * 4);
  u16* Pa = (u16*)alloc((size_t)N * 128 * 2);
  u16* Pb = (u16*)alloc((size_t)N * 128 * 2);
  u16* Wt1 = (u16*)alloc(384 * 128 * 2);
  u16* Wt2 = (u16*)alloc(128 * 128 * 2);
  u16* Wt3 = (u16*)alloc(128 * 128 * 2);
  u16 *gWt[3], *gUt[3];
  for (int i = 0; i < 3; ++i) {
    gWt[i] = (u16*)alloc(384 * 128 * 2);
    gUt[i] = (u16*)alloc(384 * 128 * 2);
  }
  int* cnt = (int*)alloc((size_t)N * 4);
  int* cursor = (int*)alloc((size_t)N * 4);
  int* partial = (int*)alloc(256 * 4);
  int* s_nbr = (int*)alloc((size_t)nslots * 4);
  int* s_eid = (int*)alloc((size_t)nslots * 4);
  int* s_dest = (int*)alloc((size_t)nslots * 4);
  u16* EFm = (u16*)alloc((size_t)E * 128 * 2);
  (void)ws_size;  // ~193 MB total

  {
    TransDesc td;
    const float* srcs[9] = {mW1, mW2, mW3, gW[0], gU[0], gW[1], gU[1], gW[2], gU[2]};
    u16* dsts[9] = {Wt1, Wt2, Wt3, gWt[0], gUt[0], gWt[1], gUt[1], gWt[2], gUt[2]};
    int Rs[9] = {384, 128, 128, 128, 128, 128, 128, 128, 128};
    int Cs[9] = {128, 128, 128, 384, 384, 384, 384, 384, 384};
    int acc = 0;
    for (int i = 0; i < 9; ++i) {
      td.src[i] = srcs[i];
      td.dst[i] = dsts[i];
      td.R[i] = Rs[i];
      td.C[i] = Cs[i];
      td.pre[i] = acc;
      acc += Rs[i] * Cs[i];
    }
    td.pre[9] = acc;
    transpose_all_kernel<<<(acc + 255) / 256, 256, 0, stream>>>(td);
  }

  // CSR slot build
  hipMemsetAsync(cnt, 0, (size_t)N * 4, stream);
  count_kernel<<<(E + 255) / 256, 256, 0, stream>>>(from_idx, to_idx, cnt, E);
  int chunk = (N + 255) / 256;
  scan1_kernel<<<256, 256, 0, stream>>>(cnt, partial, N, chunk);
  scan2_kernel<<<1, 256, 0, stream>>>(partial);
  scan3_kernel<<<256, 256, 0, stream>>>(cnt, partial, cursor, N, chunk);
  slot_kernel<<<(E + 255) / 256, 256, 0, stream>>>(from_idx, to_idx, cursor,
                                                   s_nbr, s_eid, s_dest, E);

  // fused first-layer GEMMs (node partials + EF), 128-row/512-thread tiles
  int Nb = (N + 127) / 128, Eb = (E + 127) / 128;
  gemm1_kernel<<<Nb + Eb, 512, 0, stream>>>(ns, ef, Wt1, mb1, Pa, Pb, EFm, N,
                                            E, Nb);

  // destination-sorted edge MLP + fused aggregation
  hipMemsetAsync(aggf, 0, (size_t)N * 128 * 4, stream);
  int ntiles = (nslots + 63) / 64;
  int egrid = ntiles < 512 ? ntiles : 512;
  edge_csr2_kernel<<<egrid, 512, 0, stream>>>(EFm, s_nbr, s_eid, s_dest, Wt2,
                                              Wt3, Pa, Pb, mb2, mb3, aggf,
                                              nslots, ntiles);

  int gblocks = (N + 63) / 64;
  gru3_kernel<<<gblocks, 256, 0, stream>>>(
      ns, aggf, gWt[0], gUt[0], gWt[1], gUt[1], gWt[2], gUt[2], gb[0], gc[0],
      gb[1], gc[1], gb[2], gc[2], (float*)d_out, N);
}

// Round 12
// 597.709 us; speedup vs baseline: 1.3817x; 1.3817x over previous
//
#include <hip/hip_runtime.h>

typedef unsigned short u16;
typedef __attribute__((ext_vector_type(8))) short bf16x8;
typedef __attribute__((ext_vector_type(4))) float f32x4;

__device__ inline u16 f2bf(float f) {
  unsigned int u = __float_as_uint(f);
  u += 0x7fffu + ((u >> 16) & 1u);
  return (u16)(u >> 16);
}
__device__ inline float bf2f(u16 v) {
  return __uint_as_float((unsigned)v << 16);
}

__device__ inline uint4 pack8(float4 a, float4 b) {
  uint4 r;
  r.x = (unsigned)f2bf(a.x) | ((unsigned)f2bf(a.y) << 16);
  r.y = (unsigned)f2bf(a.z) | ((unsigned)f2bf(a.w) << 16);
  r.z = (unsigned)f2bf(b.x) | ((unsigned)f2bf(b.y) << 16);
  r.w = (unsigned)f2bf(b.z) | ((unsigned)f2bf(b.w) << 16);
  return r;
}

// ---- fused one-shot weight transpose ----
struct TransDesc {
  const float* src[9];
  u16* dst[9];
  int R[9];
  int C[9];
  int pre[10];
};

__global__ void transpose_all_kernel(TransDesc td) {
  int t = blockIdx.x * 256 + threadIdx.x;
  if (t >= td.pre[9]) return;
  int seg = 0;
  while (t >= td.pre[seg + 1]) ++seg;
  int local = t - td.pre[seg];
  int C = td.C[seg], R = td.R[seg];
  int r = local / C, c = local - r * C;
  td.dst[seg][(size_t)c * R + r] = f2bf(td.src[seg][local]);
}

// ---------------- CSR slot build ----------------
__global__ void count_kernel(const int* __restrict__ fi,
                             const int* __restrict__ ti,
                             int* __restrict__ cnt, int E) {
  int e = blockIdx.x * 256 + threadIdx.x;
  if (e < E) {
    atomicAdd(&cnt[ti[e]], 1);
    atomicAdd(&cnt[fi[e]], 1);
  }
}

__global__ void scan1_kernel(const int* __restrict__ cnt,
                             int* __restrict__ partial, int N, int chunk) {
  __shared__ int sdata[256];
  int b = blockIdx.x, t = threadIdx.x;
  int base = b * chunk;
  int sum = 0;
  for (int i = t; i < chunk; i += 256) {
    int idx = base + i;
    if (idx < N) sum += cnt[idx];
  }
  sdata[t] = sum;
  __syncthreads();
  for (int s2 = 128; s2 > 0; s2 >>= 1) {
    if (t < s2) sdata[t] += sdata[t + s2];
    __syncthreads();
  }
  if (t == 0) partial[b] = sdata[0];
}

__global__ void scan2_kernel(int* __restrict__ partial) {
  __shared__ int s[256];
  int t = threadIdx.x;
  int own = partial[t];
  s[t] = own;
  __syncthreads();
  for (int d2 = 1; d2 < 256; d2 <<= 1) {
    int v = (t >= d2) ? s[t - d2] : 0;
    __syncthreads();
    s[t] += v;
    __syncthreads();
  }
  partial[t] = s[t] - own;  // exclusive
}

__global__ void scan3_kernel(const int* __restrict__ cnt,
                             const int* __restrict__ partialEx,
                             int* __restrict__ cursor, int N, int chunk) {
  __shared__ int s[256];
  int b = blockIdx.x, t = threadIdx.x;
  int base = b * chunk;
  int own = (t < chunk && base + t < N) ? cnt[base + t] : 0;
  s[t] = own;
  __syncthreads();
  for (int d2 = 1; d2 < 256; d2 <<= 1) {
    int v = (t >= d2) ? s[t - d2] : 0;
    __syncthreads();
    s[t] += v;
    __syncthreads();
  }
  int ex = s[t] - own + partialEx[b];
  if (t < chunk && base + t < N) cursor[base + t] = ex;
}

__global__ void slot_kernel(const int* __restrict__ fi,
                            const int* __restrict__ ti,
                            int* __restrict__ cursor, int* __restrict__ s_nbr,
                            int* __restrict__ s_eid, int* __restrict__ s_dest,
                            int E) {
  int e = blockIdx.x * 256 + threadIdx.x;
  if (e < E) {
    int f = fi[e], t2 = ti[e];
    int p0 = atomicAdd(&cursor[t2], 1);
    s_nbr[p0] = f;
    s_eid[p0] = e;
    s_dest[p0] = t2;
    int p1 = atomicAdd(&cursor[f], 1);
    s_nbr[p1] = t2;
    s_eid[p1] = e;
    s_dest[p1] = f;
  }
}

// ---- shared MFMA helpers (verified R1-R10) ----
__device__ inline void stage_w_512(u16* sW, const u16* __restrict__ src,
                                   int roww, int colofs, int tid) {
  int n = tid >> 2, quarter = tid & 3;
  const u16* s = src + (size_t)n * roww + colofs + quarter * 32;
#pragma unroll
  for (int q = 0; q < 4; ++q) {
    uint4 v = *(const uint4*)(s + q * 8);
    int byte = n * 256 + ((quarter * 64 + q * 16) ^ ((n & 7) << 4));
    *(uint4*)((char*)sW + byte) = v;
  }
}

__device__ inline void mfma_pass(const u16* A, const u16* W, f32x4 acc[8],
                                 int w, int lane) {
  const int cA = lane & 15;
  const int ko = (lane >> 4) * 8;
  const int arow = 16 * w + cA;
#pragma unroll
  for (int kk = 0; kk < 4; ++kk) {
    int ka = (kk * 32 + ko) * 2;
    int sx = ka ^ ((cA & 7) << 4);
    bf16x8 a = *(const bf16x8*)((const char*)A + arow * 256 + sx);
#pragma unroll
    for (int nt = 0; nt < 8; ++nt) {
      bf16x8 bb = *(const bf16x8*)((const char*)W + (nt * 16 + cA) * 256 + sx);
      acc[nt] = __builtin_amdgcn_mfma_f32_16x16x32_bf16(a, bb, acc[nt], 0, 0, 0);
    }
  }
}

__device__ inline void write_h_lds(u16* sH, const f32x4 acc[8], int w,
                                   int lane) {
#pragma unroll
  for (int nt = 0; nt < 8; ++nt) {
    int col = nt * 16 + (lane & 15);
#pragma unroll
    for (int i = 0; i < 4; ++i) {
      int rr = 16 * w + ((lane >> 4) * 4) + i;
      *(u16*)((char*)sH + rr * 256 + ((col * 2) ^ ((rr & 7) << 4))) =
          f2bf(acc[nt][i]);
    }
  }
}

// Fused first-layer GEMMs, 128 rows / 512 threads.
// blocks [0,Nb): Pa/Pb = bf16(ns@W1a/b); blocks [Nb,Nb+Eb): EFm = bf16(ef@W1c+b1)
__global__ __launch_bounds__(512) void gemm1_kernel(
    const float* __restrict__ ns, const float* __restrict__ ef,
    const u16* __restrict__ Wt1, const float* __restrict__ b1,
    u16* __restrict__ Pa, u16* __restrict__ Pb, u16* __restrict__ EFm, int N,
    int E, int Nb) {
  __shared__ u16 sA[128 * 128];
  __shared__ u16 sW[128 * 128];
  const int tid = threadIdx.x;
  const int lane = tid & 63;
  const int w = tid >> 6;
  if ((int)blockIdx.x < Nb) {
    const int r0 = blockIdx.x * 128;
    {
      int row = tid >> 2, seg = tid & 3;
      int rr = r0 + row;
      if (rr >= N) rr = N - 1;
      const float4* sx = (const float4*)(ns + (size_t)rr * 128 + seg * 32);
#pragma unroll
      for (int q = 0; q < 4; ++q) {
        int byte = row * 256 + ((seg * 64 + q * 16) ^ ((row & 7) << 4));
        *(uint4*)((char*)sA + byte) = pack8(sx[q * 2], sx[q * 2 + 1]);
      }
    }
    stage_w_512(sW, Wt1, 384, 0, tid);
    __syncthreads();
    f32x4 accA[8] = {};
    mfma_pass(sA, sW, accA, w, lane);
    __syncthreads();
    stage_w_512(sW, Wt1, 384, 128, tid);
    __syncthreads();
    f32x4 accB[8] = {};
    mfma_pass(sA, sW, accB, w, lane);
#pragma unroll
    for (int nt = 0; nt < 8; ++nt) {
      int col = nt * 16 + (lane & 15);
#pragma unroll
      for (int i = 0; i < 4; ++i) {
        int rr = 16 * w + ((lane >> 4) * 4) + i;
        int row = r0 + rr;
        if (row < N) {
          Pa[(size_t)row * 128 + col] = f2bf(accA[nt][i]);
          Pb[(size_t)row * 128 + col] = f2bf(accB[nt][i]);
        }
      }
    }
  } else {
    const int r0 = (blockIdx.x - Nb) * 128;
    {
      int row = tid >> 2, seg = tid & 3;
      int rr = r0 + row;
      if (rr >= E) rr = E - 1;
      const float4* sx = (const float4*)(ef + (size_t)rr * 128 + seg * 32);
#pragma unroll
      for (int q = 0; q < 4; ++q) {
        int byte = row * 256 + ((seg * 64 + q * 16) ^ ((row & 7) << 4));
        *(uint4*)((char*)sA + byte) = pack8(sx[q * 2], sx[q * 2 + 1]);
      }
    }
    stage_w_512(sW, Wt1, 384, 256, tid);
    __syncthreads();
    f32x4 acc[8] = {};
    mfma_pass(sA, sW, acc, w, lane);
    __syncthreads();  // all reads of sA done before overwrite
#pragma unroll
    for (int nt = 0; nt < 8; ++nt) {
      int col = nt * 16 + (lane & 15);
      float bv = b1[col];
#pragma unroll
      for (int i = 0; i < 4; ++i) {
        int rr = 16 * w + ((lane >> 4) * 4) + i;
        *(u16*)((char*)sA + rr * 256 + ((col * 2) ^ ((rr & 7) << 4))) =
            f2bf(acc[nt][i] + bv);
      }
    }
    __syncthreads();
#pragma unroll
    for (int it = 0; it < 4; ++it) {
      int task = tid + (it << 9);
      int row = task >> 4, c8 = task & 15;
      int gr = r0 + row;
      if (gr < E) {
        uint4 v = *(const uint4*)((const char*)sA + row * 256 +
                                  ((c8 << 4) ^ ((row & 7) << 4)));
        *(uint4*)(EFm + (size_t)gr * 128 + (c8 << 3)) = v;
      }
    }
  }
}

// Destination-sorted edge MLP, 64 slots/tile, W2/W3 in LDS -> 2 blocks/CU.
// (R10-verified, near its structural floor)
__global__ __launch_bounds__(512, 2) void edge_csr2_kernel(
    const u16* __restrict__ EFm, const int* __restrict__ s_nbr,
    const int* __restrict__ s_eid, const int* __restrict__ s_dest,
    const u16* __restrict__ Wt2, const u16* __restrict__ Wt3,
    const u16* __restrict__ Pa, const u16* __restrict__ Pb,
    const float* __restrict__ b2, const float* __restrict__ b3,
    float* __restrict__ aggf, int nslots, int ntiles) {
  __shared__ u16 sW2[128 * 128];
  __shared__ u16 sW3[128 * 128];
  __shared__ u16 sH[64 * 128];
  const int tid = threadIdx.x;
  const int lane = tid & 63;
  const int wv = tid >> 6;
  const int mw = wv >> 1;
  const int nw = wv & 1;
  const int l15 = lane & 15;
  const int lhi = lane >> 4;

  stage_w_512(sW2, Wt2, 128, 0, tid);
  stage_w_512(sW3, Wt3, 128, 0, tid);
  float b2f[4], b3f[4];
#pragma unroll
  for (int nt = 0; nt < 4; ++nt) {
    int col = (nw << 6) + (nt << 4) + l15;
    b2f[nt] = b2[col];
    b3f[nt] = b3[col];
  }
  __syncthreads();

  const int ra = (mw << 4) + l15;

  for (int t = blockIdx.x; t < ntiles; t += gridDim.x) {
    const int r0 = t << 6;
#pragma unroll
    for (int it = 0; it < 2; ++it) {
      int task = tid + (it << 9);
      int row = task >> 4;
      int c8 = task & 15;
      int r = r0 + row;
      int rc = r < nslots ? r : nslots - 1;
      int nbr = s_nbr[rc], eid = s_eid[rc], dst = s_dest[rc];
      uint4 efv = *(const uint4*)(EFm + (size_t)eid * 128 + (c8 << 3));
      uint4 pav = *(const uint4*)(Pa + (size_t)nbr * 128 + (c8 << 3));
      uint4 pbv = *(const uint4*)(Pb + (size_t)dst * 128 + (c8 << 3));
      const u16* pe = (const u16*)&efv;
      const u16* pa = (const u16*)&pav;
      const u16* pb = (const u16*)&pbv;
      unsigned o[4];
#pragma unroll
      for (int j = 0; j < 4; ++j) {
        float v0 = fmaxf(bf2f(pe[2 * j]) + bf2f(pa[2 * j]) + bf2f(pb[2 * j]), 0.f);
        float v1 = fmaxf(bf2f(pe[2 * j + 1]) + bf2f(pa[2 * j + 1]) + bf2f(pb[2 * j + 1]), 0.f);
        o[j] = (unsigned)f2bf(v0) | ((unsigned)f2bf(v1) << 16);
      }
      *(uint4*)((char*)sH + row * 256 + ((c8 << 4) ^ ((row & 7) << 4))) = *(uint4*)o;
    }
    __syncthreads();
    bf16x8 hA[4];
#pragma unroll
    for (int kk = 0; kk < 4; ++kk) {
      int sx = ((kk << 6) + (lhi << 4)) ^ ((ra & 7) << 4);
      hA[kk] = *(const bf16x8*)((const char*)sH + ra * 256 + sx);
    }
    f32x4 acc[4] = {};
#pragma unroll
    for (int kk = 0; kk < 4; ++kk) {
#pragma unroll
      for (int nt = 0; nt < 4; ++nt) {
        int c = (nw << 6) + (nt << 4) + l15;
        int sx = ((kk << 6) + (lhi << 4)) ^ ((c & 7) << 4);
        bf16x8 bb = *(const bf16x8*)((const char*)sW2 + c * 256 + sx);
        acc[nt] = __builtin_amdgcn_mfma_f32_16x16x32_bf16(hA[kk], bb, acc[nt], 0, 0, 0);
      }
    }
    __syncthreads();
#pragma unroll
    for (int i = 0; i < 4; ++i) {
      int rl = (mw << 4) + (lhi << 2) + i;
#pragma unroll
      for (int nt = 0; nt < 4; ++nt) {
        int col = (nw << 6) + (nt << 4) + l15;
        float v = fmaxf(acc[nt][i] + b2f[nt], 0.f);
        *(u16*)((char*)sH + rl * 256 + ((col * 2) ^ ((rl & 7) << 4))) = f2bf(v);
        acc[nt][i] = 0.f;
      }
    }
    __syncthreads();
#pragma unroll
    for (int kk = 0; kk < 4; ++kk) {
      int sx = ((kk << 6) + (lhi << 4)) ^ ((ra & 7) << 4);
      hA[kk] = *(const bf16x8*)((const char*)sH + ra * 256 + sx);
    }
#pragma unroll
    for (int kk = 0; kk < 4; ++kk) {
#pragma unroll
      for (int nt = 0; nt < 4; ++nt) {
        int c = (nw << 6) + (nt << 4) + l15;
        int sx = ((kk << 6) + (lhi << 4)) ^ ((c & 7) << 4);
        bf16x8 bb = *(const bf16x8*)((const char*)sW3 + c * 256 + sx);
        acc[nt] = __builtin_amdgcn_mfma_f32_16x16x32_bf16(hA[kk], bb, acc[nt], 0, 0, 0);
      }
    }
    __syncthreads();
#pragma unroll
    for (int i = 0; i < 4; ++i) {
      int rl = (mw << 4) + (lhi << 2) + i;
#pragma unroll
      for (int nt = 0; nt < 4; ++nt) {
        int col = (nw << 6) + (nt << 4) + l15;
        *(u16*)((char*)sH + rl * 256 + ((col * 2) ^ ((rl & 7) << 4))) =
            f2bf(acc[nt][i] + b3f[nt]);
      }
    }
    __syncthreads();
    {
      int c = tid & 127, q = tid >> 7;
      float s = 0.f;
      int prev = -1;
      int rbeg = q << 4;
#pragma unroll 4
      for (int rr = rbeg; rr < rbeg + 16; ++rr) {
        int r = r0 + rr;
        int d = (r < nslots) ? s_dest[r] : -1;
        if (d != prev) {
          if (prev >= 0) unsafeAtomicAdd(&aggf[(size_t)prev * 128 + c], s);
          prev = d;
          s = 0.f;
        }
        if (d >= 0)
          s += bf2f(*(const u16*)((const char*)sH + rr * 256 +
                                  ((c * 2) ^ ((rr & 7) << 4))));
      }
      if (prev >= 0) unsafeAtomicAdd(&aggf[(size_t)prev * 128 + c], s);
    }
    __syncthreads();
  }
}

// Fused 3-GRU chain, 512 threads / 128 rows, double-buffered weight staging
// (1 barrier per weight stage instead of 2; h handoffs wave-private).
__global__ __launch_bounds__(512, 1) void gru3_kernel(
    const float* __restrict__ ns, const float* __restrict__ aggf,
    const u16* __restrict__ g0W, const u16* __restrict__ g0U,
    const u16* __restrict__ g1W, const u16* __restrict__ g1U,
    const u16* __restrict__ g2W, const u16* __restrict__ g2U,
    const float* __restrict__ b0, const float* __restrict__ c0,
    const float* __restrict__ b1, const float* __restrict__ c1,
    const float* __restrict__ b2, const float* __restrict__ c2,
    float* __restrict__ out, int N) {
  __shared__ u16 sX[128 * 128];    // 32 KB: ns -> h1
  __shared__ u16 sG[128 * 128];    // 32 KB: agg -> h2
  __shared__ u16 sW[2][128 * 128]; // 64 KB: double-buffered weights
  const int tid = threadIdx.x;
  const int lane = tid & 63;
  const int w = tid >> 6;  // 0..7 (wave-private rows 16w..16w+15)
  const int r0 = blockIdx.x * 128;
  {
    int row = tid >> 2, seg = tid & 3;
    int rr = r0 + row;
    if (rr >= N) rr = N - 1;
    const float4* sx = (const float4*)(ns + (size_t)rr * 128 + seg * 32);
    const float4* sh = (const float4*)(aggf + (size_t)rr * 128 + seg * 32);
#pragma unroll
    for (int q = 0; q < 4; ++q) {
      int byte = row * 256 + ((seg * 64 + q * 16) ^ ((row & 7) << 4));
      *(uint4*)((char*)sX + byte) = pack8(sx[q * 2], sx[q * 2 + 1]);
      *(uint4*)((char*)sG + byte) = pack8(sh[q * 2], sh[q * 2 + 1]);
    }
  }

  // global phase schedule: 18 weight stages, order per GRU g:
  // W_r, U_r, W_z, U_z, W_n, U_n   (ph = g*6 + p; buffer = ph & 1)
  const u16* wseq[18] = {
      g0W,          g0U,          g0W + 16384, g0U + 16384, g0W + 32768, g0U + 32768,
      g1W,          g1U,          g1W + 16384, g1U + 16384, g1W + 32768, g1U + 32768,
      g2W,          g2U,          g2W + 16384, g2U + 16384, g2W + 32768, g2U + 32768};

  stage_w_512(sW[0], wseq[0], 128, 0, tid);
  __syncthreads();  // prologue: buffer 0 ready

  float hpf[8][4];

  // One pipelined pass: prefetch wseq[ph+1] into the other buffer, run MFMA
  // on the current buffer, barrier. (compile-time ph via unrolled sections)
#define PIPE_PASS(PH, ABUF, ACC)                                    \
  {                                                                 \
    if ((PH) + 1 < 18) stage_w_512(sW[((PH) + 1) & 1], wseq[(PH) + 1], 128, 0, tid); \
    mfma_pass((ABUF), sW[(PH) & 1], (ACC), w, lane);                \
    __syncthreads();                                                \
  }

  // ---------------- GRU0: x=ns(sX), h=agg(sG) ----------------
  {
    f32x4 ar[8] = {}, az[8] = {}, ai[8] = {}, ah[8] = {};
    PIPE_PASS(0, sX, ar)
    PIPE_PASS(1, sG, ar)
    PIPE_PASS(2, sX, az)
    PIPE_PASS(3, sG, az)
    PIPE_PASS(4, sX, ai)
    PIPE_PASS(5, sG, ah)
    f32x4 h1[8];
#pragma unroll
    for (int nt = 0; nt < 8; ++nt) {
      int col = nt * 16 + (lane & 15);
      float brc = b0[col] + c0[col];
      float bzc = b0[128 + col] + c0[128 + col];
      float bi = b0[256 + col];
      float bc2 = c0[256 + col];
#pragma unroll
      for (int i = 0; i < 4; ++i) {
        int rloc = 16 * w + ((lane >> 4) * 4) + i;
        int row = r0 + rloc;
        int rowc = row < N ? row : N - 1;
        float hf = aggf[(size_t)rowc * 128 + col];
        float rg = 1.f / (1.f + __expf(-(ar[nt][i] + brc)));
        float zg = 1.f / (1.f + __expf(-(az[nt][i] + bzc)));
        float pre = ai[nt][i] + bi + rg * (ah[nt][i] + bc2);
        float ng = 2.f / (1.f + __expf(-2.f * pre)) - 1.f;
        float hv = (1.f - zg) * ng + zg * hf;
        h1[nt][i] = hv;
        hpf[nt][i] = hv;
      }
    }
    write_h_lds(sX, h1, w, lane);  // sX := h1 (wave-private rows)
  }
  // ---------------- GRU1: x=agg(sG), h=h1(sX) ----------------
  {
    f32x4 ar[8] = {}, az[8] = {}, ai[8] = {}, ah[8] = {};
    PIPE_PASS(6, sG, ar)
    PIPE_PASS(7, sX, ar)
    PIPE_PASS(8, sG, az)
    PIPE_PASS(9, sX, az)
    PIPE_PASS(10, sG, ai)
    PIPE_PASS(11, sX, ah)
    f32x4 h2[8];
#pragma unroll
    for (int nt = 0; nt < 8; ++nt) {
      int col = nt * 16 + (lane & 15);
      float brc = b1[col] + c1[col];
      float bzc = b1[128 + col] + c1[128 + col];
      float bi = b1[256 + col];
      float bc2 = c1[256 + col];
#pragma unroll
      for (int i = 0; i < 4; ++i) {
        float rg = 1.f / (1.f + __expf(-(ar[nt][i] + brc)));
        float zg = 1.f / (1.f + __expf(-(az[nt][i] + bzc)));
        float pre = ai[nt][i] + bi + rg * (ah[nt][i] + bc2);
        float ng = 2.f / (1.f + __expf(-2.f * pre)) - 1.f;
        float hv = (1.f - zg) * ng + zg * hpf[nt][i];
        h2[nt][i] = hv;
        hpf[nt][i] = hv;
      }
    }
    write_h_lds(sG, h2, w, lane);  // sG := h2 (wave-private rows)
  }
  // ---------------- GRU2: x=h1(sX), h=h2(sG) -> out ----------------
  {
    f32x4 ar[8] = {}, az[8] = {}, ai[8] = {}, ah[8] = {};
    PIPE_PASS(12, sX, ar)
    PIPE_PASS(13, sG, ar)
    PIPE_PASS(14, sX, az)
    PIPE_PASS(15, sG, az)
    PIPE_PASS(16, sX, ai)
    PIPE_PASS(17, sG, ah)
#pragma unroll
    for (int nt = 0; nt < 8; ++nt) {
      int col = nt * 16 + (lane & 15);
      float brc = b2[col] + c2[col];
      float bzc = b2[128 + col] + c2[128 + col];
      float bi = b2[256 + col];
      float bc2 = c2[256 + col];
#pragma unroll
      for (int i = 0; i < 4; ++i) {
        int rloc = 16 * w + ((lane >> 4) * 4) + i;
        int row = r0 + rloc;
        if (row < N) {
          float rg = 1.f / (1.f + __expf(-(ar[nt][i] + brc)));
          float zg = 1.f / (1.f + __expf(-(az[nt][i] + bzc)));
          float pre = ai[nt][i] + bi + rg * (ah[nt][i] + bc2);
          float ng = 2.f / (1.f + __expf(-2.f * pre)) - 1.f;
          out[(size_t)row * 128 + col] = (1.f - zg) * ng + zg * hpf[nt][i];
        }
      }
    }
  }
#undef PIPE_PASS
}

extern "C" void kernel_launch(void* const* d_in, const int* in_sizes, int n_in,
                              void* d_out, int out_size, void* d_ws,
                              size_t ws_size, hipStream_t stream) {
  const float* ns = (const float*)d_in[0];
  const float* ef = (const float*)d_in[1];
  const int* from_idx = (const int*)d_in[2];
  const int* to_idx = (const int*)d_in[3];
  const float* mW1 = (const float*)d_in[5];
  const float* mb1 = (const float*)d_in[6];
  const float* mW2 = (const float*)d_in[7];
  const float* mb2 = (const float*)d_in[8];
  const float* mW3 = (const float*)d_in[9];
  const float* mb3 = (const float*)d_in[10];
  const float* gW[3] = {(const float*)d_in[11], (const float*)d_in[15], (const float*)d_in[19]};
  const float* gU[3] = {(const float*)d_in[12], (const float*)d_in[16], (const float*)d_in[20]};
  const float* gb[3] = {(const float*)d_in[13], (const float*)d_in[17], (const float*)d_in[21]};
  const float* gc[3] = {(const float*)d_in[14], (const float*)d_in[18], (const float*)d_in[22]};

  const int N = in_sizes[0] / 128;
  const int E = in_sizes[1] / 128;
  const int nslots = 2 * E;

  char* base = (char*)d_ws;
  size_t cur = 0;
  auto alloc = [&](size_t bytes) {
    size_t p = cur;
    cur = (cur + bytes + 255) & ~(size_t)255;
    return (void*)(base + p);
  };
  float* aggf = (float*)alloc((size_t)N * 128 * 4);
  u16* Pa = (u16*)alloc((size_t)N * 128 * 2);
  u16* Pb = (u16*)alloc((size_t)N * 128 * 2);
  u16* Wt1 = (u16*)alloc(384 * 128 * 2);
  u16* Wt2 = (u16*)alloc(128 * 128 * 2);
  u16* Wt3 = (u16*)alloc(128 * 128 * 2);
  u16 *gWt[3], *gUt[3];
  for (int i = 0; i < 3; ++i) {
    gWt[i] = (u16*)alloc(384 * 128 * 2);
    gUt[i] = (u16*)alloc(384 * 128 * 2);
  }
  int* cnt = (int*)alloc((size_t)N * 4);
  int* cursor = (int*)alloc((size_t)N * 4);
  int* partial = (int*)alloc(256 * 4);
  int* s_nbr = (int*)alloc((size_t)nslots * 4);
  int* s_eid = (int*)alloc((size_t)nslots * 4);
  int* s_dest = (int*)alloc((size_t)nslots * 4);
  u16* EFm = (u16*)alloc((size_t)E * 128 * 2);
  (void)ws_size;  // ~193 MB total

  {
    TransDesc td;
    const float* srcs[9] = {mW1, mW2, mW3, gW[0], gU[0], gW[1], gU[1], gW[2], gU[2]};
    u16* dsts[9] = {Wt1, Wt2, Wt3, gWt[0], gUt[0], gWt[1], gUt[1], gWt[2], gUt[2]};
    int Rs[9] = {384, 128, 128, 128, 128, 128, 128, 128, 128};
    int Cs[9] = {128, 128, 128, 384, 384, 384, 384, 384, 384};
    int acc = 0;
    for (int i = 0; i < 9; ++i) {
      td.src[i] = srcs[i];
      td.dst[i] = dsts[i];
      td.R[i] = Rs[i];
      td.C[i] = Cs[i];
      td.pre[i] = acc;
      acc += Rs[i] * Cs[i];
    }
    td.pre[9] = acc;
    transpose_all_kernel<<<(acc + 255) / 256, 256, 0, stream>>>(td);
  }

  // CSR slot build
  hipMemsetAsync(cnt, 0, (size_t)N * 4, stream);
  count_kernel<<<(E + 255) / 256, 256, 0, stream>>>(from_idx, to_idx, cnt, E);
  int chunk = (N + 255) / 256;
  scan1_kernel<<<256, 256, 0, stream>>>(cnt, partial, N, chunk);
  scan2_kernel<<<1, 256, 0, stream>>>(partial);
  scan3_kernel<<<256, 256, 0, stream>>>(cnt, partial, cursor, N, chunk);
  slot_kernel<<<(E + 255) / 256, 256, 0, stream>>>(from_idx, to_idx, cursor,
                                                   s_nbr, s_eid, s_dest, E);

  // fused first-layer GEMMs (node partials + EF), 128-row/512-thread tiles
  int Nb = (N + 127) / 128, Eb = (E + 127) / 128;
  gemm1_kernel<<<Nb + Eb, 512, 0, stream>>>(ns, ef, Wt1, mb1, Pa, Pb, EFm, N,
                                            E, Nb);

  // destination-sorted edge MLP + fused aggregation
  hipMemsetAsync(aggf, 0, (size_t)N * 128 * 4, stream);
  int ntiles = (nslots + 63) / 64;
  int egrid = ntiles < 512 ? ntiles : 512;
  edge_csr2_kernel<<<egrid, 512, 0, stream>>>(EFm, s_nbr, s_eid, s_dest, Wt2,
                                              Wt3, Pa, Pb, mb2, mb3, aggf,
                                              nslots, ntiles);

  int gblocks = (N + 127) / 128;
  gru3_kernel<<<gblocks, 512, 0, stream>>>(
      ns, aggf, gWt[0], gUt[0], gWt[1], gUt[1], gWt[2], gUt[2], gb[0], gc[0],
      gb[1], gc[1], gb[2], gc[2], (float*)d_out, N);
}